// Round 9
// baseline (446.776 us; speedup 1.0000x reference)
//
#include <hip/hip_runtime.h>
#include <cstdint>

#define BATCH 4096
#define IN_DIM 1024
#define HID 2048
#define OUT_DIM 10
#define NTASKS 10

typedef __bf16 bf16x8 __attribute__((ext_vector_type(8)));
typedef float f32x4 __attribute__((ext_vector_type(4)));
typedef __attribute__((address_space(3))) uint8_t lds_u8;
typedef const __attribute__((address_space(1))) uint8_t glb_u8;

__device__ __forceinline__ unsigned short f2bf(float f) {
    uint32_t u = __builtin_bit_cast(uint32_t, f);
    u += 0x7fffu + ((u >> 16) & 1u);   // round-to-nearest-even
    return (unsigned short)(u >> 16);
}
__device__ __forceinline__ uint32_t pk(float a, float b) {
    return (uint32_t)f2bf(a) | ((uint32_t)f2bf(b) << 16);
}
// transform 8 fp32 (two float4 per stream) -> 8 bf16 packed in uint4
__device__ __forceinline__ uint4 tf8(float4 ma, float4 mb, float4 la, float4 lb,
                                     float4 ea, float4 eb) {
    uint4 r;
    r.x = pk(ma.x + __expf(la.x) * ea.x, ma.y + __expf(la.y) * ea.y);
    r.y = pk(ma.z + __expf(la.z) * ea.z, ma.w + __expf(la.w) * ea.w);
    r.z = pk(mb.x + __expf(lb.x) * eb.x, mb.y + __expf(lb.y) * eb.y);
    r.w = pk(mb.z + __expf(lb.z) * eb.z, mb.w + __expf(lb.w) * eb.w);
    return r;
}
__device__ __forceinline__ uint4 cv8(float4 a, float4 b) {
    uint4 r;
    r.x = pk(a.x, a.y); r.y = pk(a.z, a.w);
    r.z = pk(b.x, b.y); r.w = pk(b.z, b.w);
    return r;
}

// ---------------- small: head weights (f32) + all biases ----------------
// grid 208 x 256 = 53248 float4-units exactly: [0,51200) hw, [51200,51712) b0,
// [51712,53248) b1..3. hb (100 scalars) by block 0 lanes 0-99.
__global__ __launch_bounds__(256) void bl_smallx(
    const float4* __restrict__ mh, const float4* __restrict__ lh, const float4* __restrict__ eh,
    const float4* __restrict__ mb0, const float4* __restrict__ lb0, const float4* __restrict__ eb0,
    const float4* __restrict__ mb, const float4* __restrict__ lb, const float4* __restrict__ eb,
    const float* __restrict__ mu_hb, const float* __restrict__ ls_hb, const float* __restrict__ eps_hb,
    float4* __restrict__ hw4, float4* __restrict__ b04, float4* __restrict__ bb4,
    float* __restrict__ hbf)
{
    const uint32_t u = blockIdx.x * 256 + threadIdx.x;
    if (blockIdx.x == 0 && threadIdx.x < 100)
        hbf[threadIdx.x] = mu_hb[threadIdx.x] + __expf(ls_hb[threadIdx.x]) * eps_hb[threadIdx.x];
    float4 m, l, e; float4* dst;
    if (u < 51200u)      { m = mh[u]; l = lh[u]; e = eh[u]; dst = hw4 + u; }
    else if (u < 51712u) { const uint32_t v = u - 51200u; m = mb0[v]; l = lb0[v]; e = eb0[v]; dst = b04 + v; }
    else                 { const uint32_t v = u - 51712u; m = mb[v];  l = lb[v];  e = eb[v];  dst = bb4 + v; }
    float4 r;
    r.x = m.x + __expf(l.x) * e.x;
    r.y = m.y + __expf(l.y) * e.y;
    r.z = m.z + __expf(l.z) * e.z;
    r.w = m.w + __expf(l.w) * e.w;
    *dst = r;
}

// ---------------- GEMM with FUSED weight transform ----------------
// C[4096,2048] = relu(A[4096,K] @ B[2048,K]^T + bias); B materializes only in
// LDS: staging loads mu/ls/eps fp32 streams, computes mu+exp(ls)*eps -> bf16 in
// registers, ds_writes the same swizzled layout gll would have produced
// (pre-swizzled source slot ss, linear dest + lane*16). A: bf16 gll (layers
// 1-3) or fp32 reg-stage cast (layer 0, AF32). Proven round-5 sync skeleton:
// BM=256 BN=128 BK=64, 8 waves, dbuf 96KB, 4 phases/K-tile, 7xBAR +
// 1x__syncthreads per tile. Staging issue: phase0 = 12 B-loads(t+1),
// phase1 = A(t+1); consume: phase2 tail = write B chunk0, phase3 tail =
// write B chunk1 (+A for AF32); syncthreads drains all.
#define BAR()        asm volatile("s_barrier" ::: "memory")
#define WAIT_LGKM0() do { asm volatile("s_waitcnt lgkmcnt(0)" ::: "memory"); __builtin_amdgcn_sched_barrier(0); } while (0)
#define RD_A(m, o)   (*(const bf16x8*)(ldsb + acur + (o) + (m)*2048))
#define RD_B(n, o)   (*(const bf16x8*)(ldsb + bcur + (o) + (n)*2048))
#define MFMA(d, va, vb) d = __builtin_amdgcn_mfma_f32_16x16x32_bf16(va, vb, d, 0, 0, 0)
#define STAGEA(i, kel, sl) \
    __builtin_amdgcn_global_load_lds((glb_u8*)(gA[i] + (kel)), \
        (lds_u8*)(ldsb + (uint32_t)(wave * 4 + (i)) * 1024u + (uint32_t)(sl) * 32768u), 16, 0, 0)
#define LOADB0(k4) do { Bm0a = gBm0[k4]; Bm0b = gBm0[(k4)+1]; Bl0a = gBl0[k4]; \
    Bl0b = gBl0[(k4)+1]; Be0a = gBe0[k4]; Be0b = gBe0[(k4)+1]; } while (0)
#define LOADB1(k4) do { Bm1a = gBm1[k4]; Bm1b = gBm1[(k4)+1]; Bl1a = gBl1[k4]; \
    Bl1b = gBl1[(k4)+1]; Be1a = gBe1[k4]; Be1b = gBe1[(k4)+1]; } while (0)
#define WRB0(sl) (*(uint4*)(ldsb + bD0 + (uint32_t)(sl) * 16384u) = tf8(Bm0a, Bm0b, Bl0a, Bl0b, Be0a, Be0b))
#define WRB1(sl) (*(uint4*)(ldsb + bD1 + (uint32_t)(sl) * 16384u) = tf8(Bm1a, Bm1b, Bl1a, Bl1b, Be1a, Be1b))

template <bool AF32>
__global__ __launch_bounds__(512, 1) void bl_gemm(
    const void* __restrict__ Ap,            // bf16 [4096][K] or f32 [4096][K]
    const float4* __restrict__ Bm4, const float4* __restrict__ Bl4, const float4* __restrict__ Be4,
    const float* __restrict__ bias,         // [2048]
    unsigned short* __restrict__ C,         // [4096][2048] bf16
    int K)
{
    __shared__ unsigned short lds[49152];   // 96 KB
    uint8_t* ldsb = (uint8_t*)lds;

    const int tid  = threadIdx.x;
    const int wave = tid >> 6;
    const int lane = tid & 63;
    const int swz = ((blockIdx.x & 7) << 5) | (blockIdx.x >> 3);
    const int bm = swz >> 4;
    const int bn = swz & 15;
    const int wr = wave >> 1;
    const int wc = wave & 1;
    const int lr8 = lane >> 3;
    const int ss  = (lane & 7) ^ lr8;       // pre-swizzled 16B slot
    const int K4  = K >> 2;

    // ---- A staging setup: 32 chunks, 4/wave ----
    const unsigned short* gA[4];
    const float4* gAf[4];
    #pragma unroll
    for (int i = 0; i < 4; ++i) {
        const int ca = wave * 4 + i;
        const int row = bm * 256 + ca * 8 + lr8;
        if constexpr (AF32) gAf[i] = (const float4*)Ap + (size_t)row * K4 + ss * 2;
        else                gA[i]  = (const unsigned short*)Ap + (size_t)row * K + ss * 8;
    }
    // ---- B staging setup: 16 chunks, 2/wave, fp32 triple-stream ----
    const int cb0 = wave * 2, cb1 = wave * 2 + 1;
    const int rB0 = bn * 128 + cb0 * 8 + lr8;
    const int rB1 = bn * 128 + cb1 * 8 + lr8;
    const float4* gBm0 = Bm4 + (size_t)rB0 * K4 + ss * 2;
    const float4* gBl0 = Bl4 + (size_t)rB0 * K4 + ss * 2;
    const float4* gBe0 = Be4 + (size_t)rB0 * K4 + ss * 2;
    const float4* gBm1 = Bm4 + (size_t)rB1 * K4 + ss * 2;
    const float4* gBl1 = Bl4 + (size_t)rB1 * K4 + ss * 2;
    const float4* gBe1 = Be4 + (size_t)rB1 * K4 + ss * 2;
    const uint32_t bD0 = 65536u + (uint32_t)cb0 * 1024u + (uint32_t)lane * 16u;
    const uint32_t bD1 = 65536u + (uint32_t)cb1 * 1024u + (uint32_t)lane * 16u;
    const uint32_t aD  = (uint32_t)(wave * 4) * 1024u + (uint32_t)lane * 16u;  // + i*1024

    // ---- fragment-read offsets (row stride 128B, slot ^= row&7 swizzle) ----
    const int rA = wr * 64 + (lane & 15);
    const int rB = wc * 64 + (lane & 15);
    const int ks = lane >> 4;
    const uint32_t aoff0 = (uint32_t)(rA * 128 + ((ks       ^ (rA & 7)) * 16));
    const uint32_t aoff1 = (uint32_t)(rA * 128 + (((4 | ks) ^ (rA & 7)) * 16));
    const uint32_t boff0 = (uint32_t)(rB * 128 + ((ks       ^ (rB & 7)) * 16));
    const uint32_t boff1 = (uint32_t)(rB * 128 + (((4 | ks) ^ (rB & 7)) * 16));

    f32x4 acc[4][4] = {};
    const int NT = K >> 6;

    float4 Bm0a, Bm0b, Bl0a, Bl0b, Be0a, Be0b;
    float4 Bm1a, Bm1b, Bl1a, Bl1b, Be1a, Be1b;
    float4 Aa0, Ab0, Aa1, Ab1, Aa2, Ab2, Aa3, Ab3;

    // ---- prologue: stage tile 0 into slot 0 ----
    LOADB0(0); LOADB1(0);
    if constexpr (AF32) {
        Aa0 = gAf[0][0]; Ab0 = gAf[0][1]; Aa1 = gAf[1][0]; Ab1 = gAf[1][1];
        Aa2 = gAf[2][0]; Ab2 = gAf[2][1]; Aa3 = gAf[3][0]; Ab3 = gAf[3][1];
    } else {
        STAGEA(0, 0, 0); STAGEA(1, 0, 0); STAGEA(2, 0, 0); STAGEA(3, 0, 0);
    }
    WRB0(0); WRB1(0);
    if constexpr (AF32) {
        *(uint4*)(ldsb + aD)         = cv8(Aa0, Ab0);
        *(uint4*)(ldsb + aD + 1024u) = cv8(Aa1, Ab1);
        *(uint4*)(ldsb + aD + 2048u) = cv8(Aa2, Ab2);
        *(uint4*)(ldsb + aD + 3072u) = cv8(Aa3, Ab3);
    }
    __syncthreads();

    for (int t = 0; t < NT; ++t) {
        const int cur = t & 1, nxt = cur ^ 1;
        const uint32_t acur = (uint32_t)cur * 32768u;
        const uint32_t bcur = 65536u + (uint32_t)cur * 16384u;
        const bool pf = (t + 1 < NT);
        const int k4n = (t + 1) * 16;       // float4 offset of next K-tile
        const int ktn = (t + 1) << 6;       // element offset (bf16 gll path)

        bf16x8 a0, a1, a2, a3, b0, b1, b2, b3;

        // ---- phase 0: issue next-tile B loads; MFMA kk=0 rows 0-1 ----
        if (pf) { LOADB0(k4n); LOADB1(k4n); }
        a0 = RD_A(0, aoff0); a1 = RD_A(1, aoff0);
        b0 = RD_B(0, boff0); b1 = RD_B(1, boff0); b2 = RD_B(2, boff0); b3 = RD_B(3, boff0);
        BAR(); WAIT_LGKM0();
        __builtin_amdgcn_s_setprio(1);
        MFMA(acc[0][0], a0, b0); MFMA(acc[0][1], a0, b1); MFMA(acc[0][2], a0, b2); MFMA(acc[0][3], a0, b3);
        MFMA(acc[1][0], a1, b0); MFMA(acc[1][1], a1, b1); MFMA(acc[1][2], a1, b2); MFMA(acc[1][3], a1, b3);
        __builtin_amdgcn_s_setprio(0);
        BAR();

        // ---- phase 1: issue next-tile A staging; MFMA kk=0 rows 2-3 ----
        if (pf) {
            if constexpr (AF32) {
                Aa0 = gAf[0][k4n]; Ab0 = gAf[0][k4n + 1];
                Aa1 = gAf[1][k4n]; Ab1 = gAf[1][k4n + 1];
                Aa2 = gAf[2][k4n]; Ab2 = gAf[2][k4n + 1];
                Aa3 = gAf[3][k4n]; Ab3 = gAf[3][k4n + 1];
            } else {
                STAGEA(0, ktn, nxt); STAGEA(1, ktn, nxt);
                STAGEA(2, ktn, nxt); STAGEA(3, ktn, nxt);
            }
        }
        a2 = RD_A(2, aoff0); a3 = RD_A(3, aoff0);
        BAR(); WAIT_LGKM0();
        __builtin_amdgcn_s_setprio(1);
        MFMA(acc[2][0], a2, b0); MFMA(acc[2][1], a2, b1); MFMA(acc[2][2], a2, b2); MFMA(acc[2][3], a2, b3);
        MFMA(acc[3][0], a3, b0); MFMA(acc[3][1], a3, b1); MFMA(acc[3][2], a3, b2); MFMA(acc[3][3], a3, b3);
        __builtin_amdgcn_s_setprio(0);
        BAR();

        // ---- phase 2: MFMA kk=1 rows 0-1; then transform+write B chunk0 ----
        a0 = RD_A(0, aoff1); a1 = RD_A(1, aoff1);
        b0 = RD_B(0, boff1); b1 = RD_B(1, boff1); b2 = RD_B(2, boff1); b3 = RD_B(3, boff1);
        BAR(); WAIT_LGKM0();
        __builtin_amdgcn_s_setprio(1);
        MFMA(acc[0][0], a0, b0); MFMA(acc[0][1], a0, b1); MFMA(acc[0][2], a0, b2); MFMA(acc[0][3], a0, b3);
        MFMA(acc[1][0], a1, b0); MFMA(acc[1][1], a1, b1); MFMA(acc[1][2], a1, b2); MFMA(acc[1][3], a1, b3);
        __builtin_amdgcn_s_setprio(0);
        if (pf) WRB0(nxt);
        BAR();

        // ---- phase 3: MFMA kk=1 rows 2-3; write B chunk1 (+A); dbuf swap ----
        a2 = RD_A(2, aoff1); a3 = RD_A(3, aoff1);
        BAR(); WAIT_LGKM0();
        __builtin_amdgcn_s_setprio(1);
        MFMA(acc[2][0], a2, b0); MFMA(acc[2][1], a2, b1); MFMA(acc[2][2], a2, b2); MFMA(acc[2][3], a2, b3);
        MFMA(acc[3][0], a3, b0); MFMA(acc[3][1], a3, b1); MFMA(acc[3][2], a3, b2); MFMA(acc[3][3], a3, b3);
        __builtin_amdgcn_s_setprio(0);
        if (pf) {
            WRB1(nxt);
            if constexpr (AF32) {
                const uint32_t ad = aD + (uint32_t)nxt * 32768u;
                *(uint4*)(ldsb + ad)         = cv8(Aa0, Ab0);
                *(uint4*)(ldsb + ad + 1024u) = cv8(Aa1, Ab1);
                *(uint4*)(ldsb + ad + 2048u) = cv8(Aa2, Ab2);
                *(uint4*)(ldsb + ad + 3072u) = cv8(Aa3, Ab3);
            }
        }
        __syncthreads();   // drains glls + ds_writes; fully modeled
    }

    // ---- epilogue: bias + relu + bf16 store ----
    const int col0 = bn * 128 + wc * 64 + (lane & 15);
    const int row0 = bm * 256 + wr * 64 + ((lane >> 4) << 2);
    #pragma unroll
    for (int n = 0; n < 4; ++n) {
        const int col = col0 + n * 16;
        const float bv = bias[col];
        #pragma unroll
        for (int m = 0; m < 4; ++m) {
            #pragma unroll
            for (int j = 0; j < 4; ++j) {
                float v = acc[m][n][j] + bv;
                v = v > 0.0f ? v : 0.0f;
                C[(size_t)(row0 + m * 16 + j) * HID + col] = f2bf(v);
            }
        }
    }
}

// ---------------- head ----------------
__global__ __launch_bounds__(256) void bl_head(
    const unsigned short* __restrict__ h,   // [4096][2048] bf16
    const float* __restrict__ hw,           // [10][10][2048] f32
    const float* __restrict__ hb,           // [10][10] f32
    const int* __restrict__ task,           // [4096] i32
    float* __restrict__ out)                // [4096][10] f32
{
    const int wave = threadIdx.x >> 6, lane = threadIdx.x & 63;
    const int b = blockIdx.x * 4 + wave;
    const int t = task[b];
    const float* w = hw + (size_t)t * OUT_DIM * HID;
    const unsigned short* hr = h + (size_t)b * HID;

    float acc[OUT_DIM];
    #pragma unroll
    for (int o = 0; o < OUT_DIM; ++o) acc[o] = 0.0f;

    #pragma unroll
    for (int i = 0; i < HID / 512; ++i) {
        const int k0 = (i * 64 + lane) * 8;
        const bf16x8 hv8 = *(const bf16x8*)(hr + k0);
        float hf[8];
        #pragma unroll
        for (int j = 0; j < 8; ++j) hf[j] = (float)hv8[j];
        #pragma unroll
        for (int o = 0; o < OUT_DIM; ++o) {
            const float4 w0 = *(const float4*)(w + (size_t)o * HID + k0);
            const float4 w1 = *(const float4*)(w + (size_t)o * HID + k0 + 4);
            acc[o] += hf[0]*w0.x + hf[1]*w0.y + hf[2]*w0.z + hf[3]*w0.w
                    + hf[4]*w1.x + hf[5]*w1.y + hf[6]*w1.z + hf[7]*w1.w;
        }
    }
    #pragma unroll
    for (int o = 0; o < OUT_DIM; ++o) {
        float v = acc[o];
        #pragma unroll
        for (int s = 32; s > 0; s >>= 1) v += __shfl_down(v, s, 64);
        if (lane == 0) out[(size_t)b * OUT_DIM + o] = v + hb[t * OUT_DIM + o];
    }
}

// ---------------- launch ----------------

extern "C" void kernel_launch(void* const* d_in, const int* in_sizes, int n_in,
                              void* d_out, int out_size, void* d_ws, size_t ws_size,
                              hipStream_t stream)
{
    const float* x      = (const float*)d_in[0];
    const float* mu_w0  = (const float*)d_in[1];
    const float* ls_w0  = (const float*)d_in[2];
    const float* mu_b0  = (const float*)d_in[3];
    const float* ls_b0  = (const float*)d_in[4];
    const float* mu_w   = (const float*)d_in[5];
    const float* ls_w   = (const float*)d_in[6];
    const float* mu_b   = (const float*)d_in[7];
    const float* ls_b   = (const float*)d_in[8];
    const float* mu_hw  = (const float*)d_in[9];
    const float* ls_hw  = (const float*)d_in[10];
    const float* mu_hb  = (const float*)d_in[11];
    const float* ls_hb  = (const float*)d_in[12];
    const float* eps_w0 = (const float*)d_in[13];
    const float* eps_b0 = (const float*)d_in[14];
    const float* eps_w  = (const float*)d_in[15];
    const float* eps_b  = (const float*)d_in[16];
    const float* eps_hw = (const float*)d_in[17];
    const float* eps_hb = (const float*)d_in[18];
    const int*   task   = (const int*)d_in[19];

    uint8_t* ws = (uint8_t*)d_ws;
    constexpr size_t HH4    = (size_t)HID * HID / 4;                 // float4 units per layer
    constexpr size_t H0_OFF = 0;                                     // h ping (bf16)
    constexpr size_t H1_OFF = H0_OFF + (size_t)BATCH * HID * 2;      // h pong
    constexpr size_t B_OFF  = H1_OFF + (size_t)BATCH * HID * 2;      // biases f32 [4*HID]
    constexpr size_t HW_OFF = B_OFF  + (size_t)4 * HID * 4;          // head w f32
    constexpr size_t HB_OFF = HW_OFF + (size_t)NTASKS * OUT_DIM * HID * 4;

    unsigned short* h0  = (unsigned short*)(ws + H0_OFF);
    unsigned short* h1  = (unsigned short*)(ws + H1_OFF);
    float* ball = (float*)(ws + B_OFF);
    float* hwf  = (float*)(ws + HW_OFF);
    float* hbf  = (float*)(ws + HB_OFF);

    bl_smallx<<<208, 256, 0, stream>>>(
        (const float4*)mu_hw, (const float4*)ls_hw, (const float4*)eps_hw,
        (const float4*)mu_b0, (const float4*)ls_b0, (const float4*)eps_b0,
        (const float4*)mu_b,  (const float4*)ls_b,  (const float4*)eps_b,
        mu_hb, ls_hb, eps_hb,
        (float4*)hwf, (float4*)ball, (float4*)(ball + HID), hbf);

    bl_gemm<true><<<256, 512, 0, stream>>>(
        x, (const float4*)mu_w0, (const float4*)ls_w0, (const float4*)eps_w0,
        ball, h0, IN_DIM);
    bl_gemm<false><<<256, 512, 0, stream>>>(
        h0, (const float4*)mu_w, (const float4*)ls_w, (const float4*)eps_w,
        ball + HID, h1, HID);
    bl_gemm<false><<<256, 512, 0, stream>>>(
        h1, (const float4*)mu_w + HH4, (const float4*)ls_w + HH4, (const float4*)eps_w + HH4,
        ball + 2 * HID, h0, HID);
    bl_gemm<false><<<256, 512, 0, stream>>>(
        h0, (const float4*)mu_w + 2 * HH4, (const float4*)ls_w + 2 * HH4, (const float4*)eps_w + 2 * HH4,
        ball + 3 * HID, h1, HID);

    bl_head<<<BATCH / 4, 256, 0, stream>>>(h1, hwf, hbf, task, (float*)d_out);
}

// Round 10
// 209.796 us; speedup vs baseline: 2.1296x; 2.1296x over previous
//
#include <hip/hip_runtime.h>
#include <cstdint>

#define BATCH 4096
#define IN_DIM 1024
#define HID 2048
#define OUT_DIM 10
#define NTASKS 10

typedef __bf16 bf16x8 __attribute__((ext_vector_type(8)));
typedef float f32x4 __attribute__((ext_vector_type(4)));
typedef __attribute__((address_space(3))) uint8_t lds_u8;
typedef const __attribute__((address_space(1))) uint8_t glb_u8;

__device__ __forceinline__ unsigned short f2bf(float f) {
    uint32_t u = __builtin_bit_cast(uint32_t, f);
    u += 0x7fffu + ((u >> 16) & 1u);   // round-to-nearest-even
    return (unsigned short)(u >> 16);
}

// ================= mega-stream: all elementwise transforms (round-8, proven) ==
#define C1 1048576u
#define C2 1572864u
#define C3 4718592u
#define C4 4769792u
#define C5 4770304u
#define GLL(src, ldsp) __builtin_amdgcn_global_load_lds((glb_u8*)(src), (lds_u8*)(ldsp), 16, 0, 0)

__global__ __launch_bounds__(256) void bl_stream(
    const float4* __restrict__ x4,
    const float4* __restrict__ m0, const float4* __restrict__ l0, const float4* __restrict__ e0,
    const float4* __restrict__ mw, const float4* __restrict__ lw, const float4* __restrict__ ew,
    const float4* __restrict__ mh, const float4* __restrict__ lh, const float4* __restrict__ eh,
    const float4* __restrict__ mb0, const float4* __restrict__ lb0, const float4* __restrict__ eb0,
    const float4* __restrict__ mb, const float4* __restrict__ lb, const float4* __restrict__ eb,
    const float* __restrict__ mu_hb, const float* __restrict__ ls_hb, const float* __restrict__ eps_hb,
    ushort4* __restrict__ xbf4, ushort4* __restrict__ w0b4, ushort4* __restrict__ wb4,
    float4* __restrict__ hw4, float4* __restrict__ b04, float4* __restrict__ bb4,
    float* __restrict__ hbf)
{
    __shared__ uint8_t sbuf[24576];          // 4 waves x 6KB
    const int tid = threadIdx.x, wv = tid >> 6, ln = tid & 63;

    if (blockIdx.x == 0 && tid < 100)
        hbf[tid] = mu_hb[tid] + __expf(ls_hb[tid]) * eps_hb[tid];

    const int w = blockIdx.x * 4 + wv;
    const int niter = 18 + (w < 832 ? 1 : 0);
    const uint32_t u0 = (uint32_t)(w * 18 + (w < 832 ? w : 832)) * 64u + (uint32_t)ln;
    uint8_t* wl = sbuf + wv * 6144;

    #define SEG_SRC(u, pa, pb, pc)                                               \
        do {                                                                     \
            uint32_t _u = (u);                                                   \
            if (_u < C1)      { pa = x4 + _u; pb = pa; pc = pa; }                \
            else if (_u < C2) { uint32_t v = _u - C1; pa = m0 + v; pb = l0 + v; pc = e0 + v; } \
            else if (_u < C3) { uint32_t v = _u - C2; pa = mw + v; pb = lw + v; pc = ew + v; } \
            else if (_u < C4) { uint32_t v = _u - C3; pa = mh + v; pb = lh + v; pc = eh + v; } \
            else if (_u < C5) { uint32_t v = _u - C4; pa = mb0 + v; pb = lb0 + v; pc = eb0 + v; } \
            else              { uint32_t v = _u - C5; pa = mb + v; pb = lb + v; pc = eb + v; } \
        } while (0)

    {
        const float4 *pa, *pb, *pc;
        SEG_SRC(u0, pa, pb, pc);
        GLL(pa, wl); GLL(pb, wl + 1024); GLL(pc, wl + 2048);
    }

    for (int it = 0; it < niter; ++it) {
        const int cb = it & 1;
        if (it + 1 < niter) {
            const float4 *pa, *pb, *pc;
            SEG_SRC(u0 + (uint32_t)(it + 1) * 64u, pa, pb, pc);
            uint8_t* nb = wl + (cb ^ 1) * 3072;
            GLL(pa, nb); GLL(pb, nb + 1024); GLL(pc, nb + 2048);
            asm volatile("s_waitcnt vmcnt(3)" ::: "memory");
        } else {
            asm volatile("s_waitcnt vmcnt(0)" ::: "memory");
        }
        const uint8_t* rb = wl + cb * 3072;
        const float4 m = *(const float4*)(rb + ln * 16);
        const float4 l = *(const float4*)(rb + 1024 + ln * 16);
        const float4 e = *(const float4*)(rb + 2048 + ln * 16);

        const uint32_t u = u0 + (uint32_t)it * 64u;
        if (u < C1) {
            ushort4 r;
            r.x = f2bf(m.x); r.y = f2bf(m.y); r.z = f2bf(m.z); r.w = f2bf(m.w);
            xbf4[u] = r;
        } else {
            float4 t;
            t.x = m.x + __expf(l.x) * e.x;
            t.y = m.y + __expf(l.y) * e.y;
            t.z = m.z + __expf(l.z) * e.z;
            t.w = m.w + __expf(l.w) * e.w;
            if (u < C3) {
                ushort4 r;
                r.x = f2bf(t.x); r.y = f2bf(t.y); r.z = f2bf(t.z); r.w = f2bf(t.w);
                if (u < C2) w0b4[u - C1] = r; else wb4[u - C2] = r;
            } else {
                if (u < C4) hw4[u - C3] = t;
                else if (u < C5) b04[u - C4] = t;
                else bb4[u - C5] = t;
            }
        }
    }
    #undef SEG_SRC
}

// ---------------- GEMM: C[4096,2048] = relu(A[4096,K] @ B[2048,K]^T + bias)
// Round-10 change (T4, the m218 lever): 3-slot LDS rotation (144KB) with
// depth-2 prefetch and COUNTED vmcnt — no __syncthreads in the main loop.
// During tile t, stage(t+2) -> slot (t+2)%3; at tile end s_waitcnt vmcnt(6)
// (own stage(t+1) landed, stage(t+2)'s 6 stay in flight) + raw s_barrier with
// memory clobber. WAR safe: slot is re-written 3 tiles after its last ds_read,
// and all ds_reads drain at each phase's lgkmcnt(0). RAW safe: per-wave vmcnt
// before barrier covers all waves' staging of the next slot.
#define BAR()        asm volatile("s_barrier" ::: "memory")
#define WAIT_LGKM0() do { asm volatile("s_waitcnt lgkmcnt(0)" ::: "memory"); __builtin_amdgcn_sched_barrier(0); } while (0)
#define RD_A(m, o)   (*(const bf16x8*)(ldsb + acur + (o) + (m)*2048))
#define RD_B(n, o)   (*(const bf16x8*)(ldsb + bcur + (o) + (n)*2048))
#define MFMA(d, va, vb) d = __builtin_amdgcn_mfma_f32_16x16x32_bf16(va, vb, d, 0, 0, 0)
#define STAGEI(i, kel, sl) \
    __builtin_amdgcn_global_load_lds((glb_u8*)(gsrc[i] + (kel)), \
        (lds_u8*)(ldsb + ldst[i] + (uint32_t)(sl) * smul[i]), 16, 0, 0)

__global__ __launch_bounds__(512, 1) void bl_gemm(
    const unsigned short* __restrict__ A,   // [4096][K] bf16
    const unsigned short* __restrict__ B,   // [2048][K] bf16
    const float* __restrict__ bias,         // [2048]
    unsigned short* __restrict__ C,         // [4096][2048] bf16
    int K)
{
    // LDS 144KB: A slots 0/32K/64K (256x64 bf16), B slots 96K + s*16K (128x64)
    __shared__ unsigned short lds[73728];
    uint8_t* ldsb = (uint8_t*)lds;

    const int tid  = threadIdx.x;
    const int wave = tid >> 6;
    const int lane = tid & 63;
    const int swz = ((blockIdx.x & 7) << 5) | (blockIdx.x >> 3);
    const int bm = swz >> 4;
    const int bn = swz & 15;
    const int wr = wave >> 1;
    const int wc = wave & 1;

    const int lr8 = lane >> 3;
    const int ss  = (lane & 7) ^ lr8;
    const unsigned short* gsrc[6];
    uint32_t ldst[6], smul[6];
    #pragma unroll
    for (int i = 0; i < 6; ++i) {
        const int c = wave * 6 + i;
        if (c < 32) {
            gsrc[i] = A + (size_t)(bm * 256 + c * 8 + lr8) * K + ss * 8;
            ldst[i] = (uint32_t)c * 1024u;
            smul[i] = 32768u;
        } else {
            gsrc[i] = B + (size_t)(bn * 128 + (c - 32) * 8 + lr8) * K + ss * 8;
            ldst[i] = 98304u + (uint32_t)(c - 32) * 1024u;
            smul[i] = 16384u;
        }
    }

    const int rA = wr * 64 + (lane & 15);
    const int rB = wc * 64 + (lane & 15);
    const int ks = lane >> 4;
    const uint32_t aoff0 = (uint32_t)(rA * 128 + ((ks       ^ (rA & 7)) * 16));
    const uint32_t aoff1 = (uint32_t)(rA * 128 + (((4 | ks) ^ (rA & 7)) * 16));
    const uint32_t boff0 = (uint32_t)(rB * 128 + ((ks       ^ (rB & 7)) * 16));
    const uint32_t boff1 = (uint32_t)(rB * 128 + (((4 | ks) ^ (rB & 7)) * 16));

    f32x4 acc[4][4] = {};
    const int NT = K >> 6;

    // ---- prologue: stage tiles 0,1 into slots 0,1; wait own 6 oldest ----
    STAGEI(0, 0, 0); STAGEI(1, 0, 0); STAGEI(2, 0, 0);
    STAGEI(3, 0, 0); STAGEI(4, 0, 0); STAGEI(5, 0, 0);
    STAGEI(0, 64, 1); STAGEI(1, 64, 1); STAGEI(2, 64, 1);
    STAGEI(3, 64, 1); STAGEI(4, 64, 1); STAGEI(5, 64, 1);
    asm volatile("s_waitcnt vmcnt(6)" ::: "memory");
    BAR();

    int cur = 0;
    for (int t = 0; t < NT; ++t) {
        const uint32_t acur = (uint32_t)cur * 32768u;
        const uint32_t bcur = 98304u + (uint32_t)cur * 16384u;
        const bool pf2 = (t + 2 < NT);
        int s2 = cur + 2; if (s2 >= 3) s2 -= 3;       // slot for tile t+2
        const int kt2 = (t + 2) << 6;

        bf16x8 a0, a1, a2, a3, b0, b1, b2, b3;

        // ---- phase 0: frags kk=0 rows 0-1; issue first half of stage(t+2) ----
        a0 = RD_A(0, aoff0); a1 = RD_A(1, aoff0);
        b0 = RD_B(0, boff0); b1 = RD_B(1, boff0); b2 = RD_B(2, boff0); b3 = RD_B(3, boff0);
        if (pf2) { STAGEI(0, kt2, s2); STAGEI(1, kt2, s2); STAGEI(2, kt2, s2); }
        BAR(); WAIT_LGKM0();
        __builtin_amdgcn_s_setprio(1);
        MFMA(acc[0][0], a0, b0); MFMA(acc[0][1], a0, b1); MFMA(acc[0][2], a0, b2); MFMA(acc[0][3], a0, b3);
        MFMA(acc[1][0], a1, b0); MFMA(acc[1][1], a1, b1); MFMA(acc[1][2], a1, b2); MFMA(acc[1][3], a1, b3);
        __builtin_amdgcn_s_setprio(0);
        BAR();

        // ---- phase 1: frags kk=0 rows 2-3; issue second half of stage(t+2) ----
        a2 = RD_A(2, aoff0); a3 = RD_A(3, aoff0);
        if (pf2) { STAGEI(3, kt2, s2); STAGEI(4, kt2, s2); STAGEI(5, kt2, s2); }
        BAR(); WAIT_LGKM0();
        __builtin_amdgcn_s_setprio(1);
        MFMA(acc[2][0], a2, b0); MFMA(acc[2][1], a2, b1); MFMA(acc[2][2], a2, b2); MFMA(acc[2][3], a2, b3);
        MFMA(acc[3][0], a3, b0); MFMA(acc[3][1], a3, b1); MFMA(acc[3][2], a3, b2); MFMA(acc[3][3], a3, b3);
        __builtin_amdgcn_s_setprio(0);
        BAR();

        // ---- phase 2: frags kk=1 rows 0-1 ----
        a0 = RD_A(0, aoff1); a1 = RD_A(1, aoff1);
        b0 = RD_B(0, boff1); b1 = RD_B(1, boff1); b2 = RD_B(2, boff1); b3 = RD_B(3, boff1);
        BAR(); WAIT_LGKM0();
        __builtin_amdgcn_s_setprio(1);
        MFMA(acc[0][0], a0, b0); MFMA(acc[0][1], a0, b1); MFMA(acc[0][2], a0, b2); MFMA(acc[0][3], a0, b3);
        MFMA(acc[1][0], a1, b0); MFMA(acc[1][1], a1, b1); MFMA(acc[1][2], a1, b2); MFMA(acc[1][3], a1, b3);
        __builtin_amdgcn_s_setprio(0);
        BAR();

        // ---- phase 3: frags kk=1 rows 2-3; COUNTED vmcnt at tile boundary ----
        a2 = RD_A(2, aoff1); a3 = RD_A(3, aoff1);
        BAR(); WAIT_LGKM0();
        __builtin_amdgcn_s_setprio(1);
        MFMA(acc[2][0], a2, b0); MFMA(acc[2][1], a2, b1); MFMA(acc[2][2], a2, b2); MFMA(acc[2][3], a2, b3);
        MFMA(acc[3][0], a3, b0); MFMA(acc[3][1], a3, b1); MFMA(acc[3][2], a3, b2); MFMA(acc[3][3], a3, b3);
        __builtin_amdgcn_s_setprio(0);
        if (pf2)              { asm volatile("s_waitcnt vmcnt(6)" ::: "memory"); }
        else if (t + 1 < NT)  { asm volatile("s_waitcnt vmcnt(0)" ::: "memory"); }
        BAR();

        cur = (cur == 2) ? 0 : cur + 1;
    }

    const int col0 = bn * 128 + wc * 64 + (lane & 15);
    const int row0 = bm * 256 + wr * 64 + ((lane >> 4) << 2);
    #pragma unroll
    for (int n = 0; n < 4; ++n) {
        const int col = col0 + n * 16;
        const float bv = bias[col];
        #pragma unroll
        for (int m = 0; m < 4; ++m) {
            #pragma unroll
            for (int j = 0; j < 4; ++j) {
                float v = acc[m][n][j] + bv;
                v = v > 0.0f ? v : 0.0f;
                C[(size_t)(row0 + m * 16 + j) * HID + col] = f2bf(v);
            }
        }
    }
}

// ---------------- head ----------------
__global__ __launch_bounds__(256) void bl_head(
    const unsigned short* __restrict__ h,   // [4096][2048] bf16
    const float* __restrict__ hw,           // [10][10][2048] f32
    const float* __restrict__ hb,           // [10][10] f32
    const int* __restrict__ task,           // [4096] i32
    float* __restrict__ out)                // [4096][10] f32
{
    const int wave = threadIdx.x >> 6, lane = threadIdx.x & 63;
    const int b = blockIdx.x * 4 + wave;
    const int t = task[b];
    const float* w = hw + (size_t)t * OUT_DIM * HID;
    const unsigned short* hr = h + (size_t)b * HID;

    float acc[OUT_DIM];
    #pragma unroll
    for (int o = 0; o < OUT_DIM; ++o) acc[o] = 0.0f;

    #pragma unroll
    for (int i = 0; i < HID / 512; ++i) {
        const int k0 = (i * 64 + lane) * 8;
        const bf16x8 hv8 = *(const bf16x8*)(hr + k0);
        float hf[8];
        #pragma unroll
        for (int j = 0; j < 8; ++j) hf[j] = (float)hv8[j];
        #pragma unroll
        for (int o = 0; o < OUT_DIM; ++o) {
            const float4 w0 = *(const float4*)(w + (size_t)o * HID + k0);
            const float4 w1 = *(const float4*)(w + (size_t)o * HID + k0 + 4);
            acc[o] += hf[0]*w0.x + hf[1]*w0.y + hf[2]*w0.z + hf[3]*w0.w
                    + hf[4]*w1.x + hf[5]*w1.y + hf[6]*w1.z + hf[7]*w1.w;
        }
    }
    #pragma unroll
    for (int o = 0; o < OUT_DIM; ++o) {
        float v = acc[o];
        #pragma unroll
        for (int s = 32; s > 0; s >>= 1) v += __shfl_down(v, s, 64);
        if (lane == 0) out[(size_t)b * OUT_DIM + o] = v + hb[t * OUT_DIM + o];
    }
}

// ---------------- launch ----------------

extern "C" void kernel_launch(void* const* d_in, const int* in_sizes, int n_in,
                              void* d_out, int out_size, void* d_ws, size_t ws_size,
                              hipStream_t stream)
{
    const float* x      = (const float*)d_in[0];
    const float* mu_w0  = (const float*)d_in[1];
    const float* ls_w0  = (const float*)d_in[2];
    const float* mu_b0  = (const float*)d_in[3];
    const float* ls_b0  = (const float*)d_in[4];
    const float* mu_w   = (const float*)d_in[5];
    const float* ls_w   = (const float*)d_in[6];
    const float* mu_b   = (const float*)d_in[7];
    const float* ls_b   = (const float*)d_in[8];
    const float* mu_hw  = (const float*)d_in[9];
    const float* ls_hw  = (const float*)d_in[10];
    const float* mu_hb  = (const float*)d_in[11];
    const float* ls_hb  = (const float*)d_in[12];
    const float* eps_w0 = (const float*)d_in[13];
    const float* eps_b0 = (const float*)d_in[14];
    const float* eps_w  = (const float*)d_in[15];
    const float* eps_b  = (const float*)d_in[16];
    const float* eps_hw = (const float*)d_in[17];
    const float* eps_hb = (const float*)d_in[18];
    const int*   task   = (const int*)d_in[19];

    uint8_t* ws = (uint8_t*)d_ws;
    constexpr size_t HH     = (size_t)HID * HID;
    constexpr size_t X_OFF  = 0;
    constexpr size_t W0_OFF = X_OFF  + (size_t)BATCH * IN_DIM * 2;       // x bf16
    constexpr size_t W_OFF  = W0_OFF + (size_t)HID * IN_DIM * 2;         // w0 bf16
    constexpr size_t H0_OFF = W_OFF  + 3 * HH * 2;                       // w1..3 bf16
    constexpr size_t H1_OFF = H0_OFF + (size_t)BATCH * HID * 2;          // h ping
    constexpr size_t B_OFF  = H1_OFF + (size_t)BATCH * HID * 2;          // h pong
    constexpr size_t HW_OFF = B_OFF  + (size_t)4 * HID * 4;              // biases f32
    constexpr size_t HB_OFF = HW_OFF + (size_t)NTASKS * OUT_DIM * HID * 4;

    unsigned short* xbf = (unsigned short*)(ws + X_OFF);
    unsigned short* w0b = (unsigned short*)(ws + W0_OFF);
    unsigned short* wb  = (unsigned short*)(ws + W_OFF);
    unsigned short* h0  = (unsigned short*)(ws + H0_OFF);
    unsigned short* h1  = (unsigned short*)(ws + H1_OFF);
    float* ball = (float*)(ws + B_OFF);
    float* hwf  = (float*)(ws + HW_OFF);
    float* hbf  = (float*)(ws + HB_OFF);

    bl_stream<<<1024, 256, 0, stream>>>(
        (const float4*)x,
        (const float4*)mu_w0, (const float4*)ls_w0, (const float4*)eps_w0,
        (const float4*)mu_w,  (const float4*)ls_w,  (const float4*)eps_w,
        (const float4*)mu_hw, (const float4*)ls_hw, (const float4*)eps_hw,
        (const float4*)mu_b0, (const float4*)ls_b0, (const float4*)eps_b0,
        (const float4*)mu_b,  (const float4*)ls_b,  (const float4*)eps_b,
        mu_hb, ls_hb, eps_hb,
        (ushort4*)xbf, (ushort4*)w0b, (ushort4*)wb,
        (float4*)hwf, (float4*)ball, (float4*)(ball + HID), hbf);

    bl_gemm<<<256, 512, 0, stream>>>(xbf, w0b, ball,             h0, IN_DIM);
    bl_gemm<<<256, 512, 0, stream>>>(h0, wb,                     ball + HID,   h1, HID);
    bl_gemm<<<256, 512, 0, stream>>>(h1, wb + HH,                ball + 2*HID, h0, HID);
    bl_gemm<<<256, 512, 0, stream>>>(h0, wb + 2*HH,              ball + 3*HID, h1, HID);

    bl_head<<<BATCH / 4, 256, 0, stream>>>(h1, hwf, hbf, task, (float*)d_out);
}